// Round 1
// baseline (266.131 us; speedup 1.0000x reference)
//
#include <hip/hip_runtime.h>
#include <hip/hip_bf16.h>

constexpr int NR = 12288;   // nodes
constexpr int KF = 256;     // in features
constexpr int DF = 128;     // out features
#define NEGBIG (-1e30f)

typedef __attribute__((ext_vector_type(8))) __bf16 bf16x8;
typedef __attribute__((ext_vector_type(4))) float  f32x4;

__device__ __forceinline__ unsigned short f2bf(float f) {
    union { float f; unsigned u; } v; v.f = f;
    unsigned r = v.u + 0x7FFFu + ((v.u >> 16) & 1u);
    return (unsigned short)(r >> 16);
}

// ---------------- Kernel A: h = x @ W (fp32), also hbT = h^T in bf16 --------
// grid 192 blocks x 256 thr; block tile 64 rows x 128 cols; K-tiles of 64.
__global__ __launch_bounds__(256) void k_gemm_h(
    const float* __restrict__ x, const float* __restrict__ W,
    float* __restrict__ h, unsigned short* __restrict__ hbT)
{
    __shared__ __align__(16) float xs[64][65];
    __shared__ __align__(16) float ws[64][132];
    const int t  = threadIdx.x;
    const int tx = t & 15, ty = t >> 4;
    const int rowbase = blockIdx.x * 64;

    float acc[4][8];
#pragma unroll
    for (int i = 0; i < 4; ++i)
#pragma unroll
        for (int j = 0; j < 8; ++j) acc[i][j] = 0.f;

    for (int kt = 0; kt < KF; kt += 64) {
        {   // stage x tile [64][64]
            int row = t >> 2, k0 = (t & 3) * 16;
            const float4* src = (const float4*)(x + (size_t)(rowbase + row) * KF + kt + k0);
            float4 v0 = src[0], v1 = src[1], v2 = src[2], v3 = src[3];
            xs[row][k0+ 0]=v0.x; xs[row][k0+ 1]=v0.y; xs[row][k0+ 2]=v0.z; xs[row][k0+ 3]=v0.w;
            xs[row][k0+ 4]=v1.x; xs[row][k0+ 5]=v1.y; xs[row][k0+ 6]=v1.z; xs[row][k0+ 7]=v1.w;
            xs[row][k0+ 8]=v2.x; xs[row][k0+ 9]=v2.y; xs[row][k0+10]=v2.z; xs[row][k0+11]=v2.w;
            xs[row][k0+12]=v3.x; xs[row][k0+13]=v3.y; xs[row][k0+14]=v3.z; xs[row][k0+15]=v3.w;
        }
        {   // stage W tile [64][128]
            int k = t >> 2, c0 = (t & 3) * 32;
            const float4* src = (const float4*)(W + (size_t)(kt + k) * DF + c0);
#pragma unroll
            for (int j = 0; j < 8; ++j)
                *(float4*)&ws[k][c0 + j * 4] = src[j];
        }
        __syncthreads();
#pragma unroll 4
        for (int k = 0; k < 64; ++k) {
            float xv[4];
#pragma unroll
            for (int ri = 0; ri < 4; ++ri) xv[ri] = xs[ty * 4 + ri][k];
            float4 w0 = *(float4*)&ws[k][tx * 8];
            float4 w1 = *(float4*)&ws[k][tx * 8 + 4];
#pragma unroll
            for (int ri = 0; ri < 4; ++ri) {
                acc[ri][0] += xv[ri] * w0.x; acc[ri][1] += xv[ri] * w0.y;
                acc[ri][2] += xv[ri] * w0.z; acc[ri][3] += xv[ri] * w0.w;
                acc[ri][4] += xv[ri] * w1.x; acc[ri][5] += xv[ri] * w1.y;
                acc[ri][6] += xv[ri] * w1.z; acc[ri][7] += xv[ri] * w1.w;
            }
        }
        __syncthreads();
    }
#pragma unroll
    for (int ri = 0; ri < 4; ++ri) {
        int row = rowbase + ty * 4 + ri;
        *(float4*)(h + (size_t)row * DF + tx * 8)     = make_float4(acc[ri][0], acc[ri][1], acc[ri][2], acc[ri][3]);
        *(float4*)(h + (size_t)row * DF + tx * 8 + 4) = make_float4(acc[ri][4], acc[ri][5], acc[ri][6], acc[ri][7]);
    }
#pragma unroll
    for (int ci = 0; ci < 8; ++ci) {
        int col = tx * 8 + ci;
        ushort4 u;
        u.x = f2bf(acc[0][ci]); u.y = f2bf(acc[1][ci]);
        u.z = f2bf(acc[2][ci]); u.w = f2bf(acc[3][ci]);
        *(ushort4*)(hbT + (size_t)col * NR + rowbase + ty * 4) = u;
    }
}

// ---------------- Kernel B: s1 = h@a1, s2 = h@a2 ----------------------------
__global__ __launch_bounds__(256) void k_s12(
    const float* __restrict__ h, const float* __restrict__ a1,
    const float* __restrict__ a2, float* __restrict__ s1, float* __restrict__ s2)
{
    const int lane = threadIdx.x & 63;
    const int row  = blockIdx.x * 4 + (threadIdx.x >> 6);
    const float* hr = h + (size_t)row * DF;
    float h0 = hr[lane], h1 = hr[lane + 64];
    float p1 = h0 * a1[lane] + h1 * a1[lane + 64];
    float p2 = h0 * a2[lane] + h1 * a2[lane + 64];
#pragma unroll
    for (int off = 32; off > 0; off >>= 1) {
        p1 += __shfl_xor(p1, off);
        p2 += __shfl_xor(p2, off);
    }
    if (lane == 0) { s1[row] = p1; s2[row] = p2; }
}

// ---------------- Kernel C: flash attention over adj ------------------------
// grid (192 row-blocks, CH chunks) x 256 thr (4 waves x 16 rows).
__global__ __launch_bounds__(256) void k_flash(
    const int* __restrict__ adj, const unsigned short* __restrict__ hbT,
    const float* __restrict__ s1, const float* __restrict__ s2,
    float* __restrict__ num, float* __restrict__ mC, float* __restrict__ lC,
    int CW)
{
    __shared__ __align__(16) unsigned short hbt[128][40];  // pad 32->40: conflict-free b128
    const int t    = threadIdx.x;
    const int wid  = t >> 6, lane = t & 63;
    const int r    = lane & 15, g = lane >> 4;
    const int rowb = blockIdx.x * 64;
    const int prow = rowb + wid * 16 + r;     // this lane's P row
    const int chunk = blockIdx.y;
    const int j0base = chunk * CW;

    const float s2r = s2[prow];
    float m = NEGBIG, lpart = 0.f;
    f32x4 acc[8];
#pragma unroll
    for (int f = 0; f < 8; ++f) acc[f] = f32x4{0.f, 0.f, 0.f, 0.f};

    const int*   ap = adj + (size_t)prow * NR + j0base + g * 8;
    const float* sp = s1 + j0base + g * 8;
    const int sf = t >> 1, sc = (t & 1) * 16;
    const unsigned short* hsrc = hbT + (size_t)sf * NR + j0base + sc;

    const int nsteps = CW >> 5;
    for (int it = 0; it < nsteps; ++it) {
        // stage hbT tile [128 feats][32 cols] into LDS (linear, padded)
        bf16x8 v0 = *(const bf16x8*)(hsrc);
        bf16x8 v1 = *(const bf16x8*)(hsrc + 8);
        hsrc += 32;
        *(bf16x8*)&hbt[sf][sc]     = v0;
        *(bf16x8*)&hbt[sf][sc + 8] = v1;
        __syncthreads();

        const int4   aa = *(const int4*)(ap);
        const int4   ab = *(const int4*)(ap + 4);
        const float4 sa = *(const float4*)(sp);
        const float4 sb = *(const float4*)(sp + 4);
        ap += 32; sp += 32;

        int   msk[8] = {aa.x, aa.y, aa.z, aa.w, ab.x, ab.y, ab.z, ab.w};
        float ev[8]  = {sa.x, sa.y, sa.z, sa.w, sb.x, sb.y, sb.z, sb.w};
#pragma unroll
        for (int i = 0; i < 8; ++i) {
            float v = ev[i] + s2r;
            v = fmaxf(v, 0.2f * v);              // LeakyReLU
            ev[i] = (msk[i] > 0) ? v : NEGBIG;   // adjacency mask
        }
        float tm = fmaxf(fmaxf(fmaxf(ev[0], ev[1]), fmaxf(ev[2], ev[3])),
                         fmaxf(fmaxf(ev[4], ev[5]), fmaxf(ev[6], ev[7])));
        tm = fmaxf(tm, __shfl_xor(tm, 16));
        tm = fmaxf(tm, __shfl_xor(tm, 32));
        const float mnew = fmaxf(m, tm);
        const float al   = __expf(m - mnew);
        m = mnew;

        float ps = 0.f;
        bf16x8 pfrag;
#pragma unroll
        for (int i = 0; i < 8; ++i) {
            float p = (msk[i] > 0) ? __expf(ev[i] - mnew) : 0.f;
            ps += p;
            pfrag[i] = (__bf16)p;
        }
        lpart = lpart * al + ps;

        float a4[4];
#pragma unroll
        for (int q = 0; q < 4; ++q) a4[q] = __shfl(al, (g << 2) | q);
#pragma unroll
        for (int f = 0; f < 8; ++f) {
            acc[f][0] *= a4[0]; acc[f][1] *= a4[1];
            acc[f][2] *= a4[2]; acc[f][3] *= a4[3];
        }
#pragma unroll
        for (int f = 0; f < 8; ++f) {
            bf16x8 bfrag = *(const bf16x8*)&hbt[f * 16 + r][g * 8];
            acc[f] = __builtin_amdgcn_mfma_f32_16x16x32_bf16(pfrag, bfrag, acc[f], 0, 0, 0);
        }
        __syncthreads();
    }

    lpart += __shfl_xor(lpart, 16);
    lpart += __shfl_xor(lpart, 32);
    if (g == 0) {
        mC[(size_t)chunk * NR + prow] = m;
        lC[(size_t)chunk * NR + prow] = lpart;
    }
    float* nb = num + (size_t)chunk * NR * DF;
#pragma unroll
    for (int f = 0; f < 8; ++f)
#pragma unroll
        for (int q = 0; q < 4; ++q) {
            int row = rowb + wid * 16 + g * 4 + q;   // C/D layout: row=(lane>>4)*4+reg
            nb[(size_t)row * DF + f * 16 + r] = acc[f][q];
        }
}

// ---------------- Kernel D: combine chunk partials --------------------------
__global__ __launch_bounds__(256) void k_comb(
    const float* __restrict__ num, const float* __restrict__ mC,
    const float* __restrict__ lC, float* __restrict__ out, int CH)
{
    const int t   = threadIdx.x;
    const int row = blockIdx.x * 2 + (t >> 7);
    const int f   = t & 127;
    float M = NEGBIG;
    for (int c = 0; c < CH; ++c) M = fmaxf(M, mC[(size_t)c * NR + row]);
    float L = 0.f, o = 0.f;
    for (int c = 0; c < CH; ++c) {
        float w = __expf(mC[(size_t)c * NR + row] - M);
        L += lC[(size_t)c * NR + row] * w;
        o += num[(size_t)c * NR * DF + (size_t)row * DF + f] * w;
    }
    out[(size_t)row * DF + f] = o / L;
}

extern "C" void kernel_launch(void* const* d_in, const int* in_sizes, int n_in,
                              void* d_out, int out_size, void* d_ws, size_t ws_size,
                              hipStream_t stream)
{
    const float* x   = (const float*)d_in[0];
    const int*   adj = (const int*)d_in[1];
    const float* W   = (const float*)d_in[2];
    const float* a1  = (const float*)d_in[3];
    const float* a2  = (const float*)d_in[4];
    float* out = (float*)d_out;

    char* p = (char*)d_ws;
    float*          h   = (float*)p;          p += (size_t)NR * DF * 4;
    unsigned short* hbT = (unsigned short*)p; p += (size_t)DF * NR * 2;
    float*          s1  = (float*)p;          p += (size_t)NR * 4;
    float*          s2  = (float*)p;          p += (size_t)NR * 4;
    size_t base = (size_t)(p - (char*)d_ws);
    size_t per  = (size_t)NR * DF * 4 + 2 * (size_t)NR * 4;
    int CH = 4;
    while (CH > 1 && base + (size_t)CH * per > ws_size) CH >>= 1;
    float* numb = (float*)p; p += (size_t)CH * NR * DF * 4;
    float* mC   = (float*)p; p += (size_t)CH * NR * 4;
    float* lC   = (float*)p;

    k_gemm_h<<<NR / 64, 256, 0, stream>>>(x, W, h, hbT);
    k_s12<<<NR / 4, 256, 0, stream>>>(h, a1, a2, s1, s2);
    k_flash<<<dim3(NR / 64, CH), 256, 0, stream>>>(adj, hbT, s1, s2, numb, mC, lC, NR / CH);
    k_comb<<<NR / 2, 256, 0, stream>>>(numb, mC, lC, out, CH);
}